// Round 2
// baseline (712.832 us; speedup 1.0000x reference)
//
#include <hip/hip_runtime.h>

typedef __attribute__((ext_vector_type(8))) short short8;
typedef __attribute__((ext_vector_type(4))) float f32x4;

#define NPTS 8192
#define NB 2
#define KNN 16
#define KP 20
#define LDX 168
#define LDH 136

__device__ inline ushort f2bf(float x){
  unsigned u = __float_as_uint(x);
  return (ushort)((u + 0x7FFFu + ((u >> 16) & 1u)) >> 16);
}
__device__ inline float leaky(float x){ return x > 0.f ? x : 0.1f * x; }
__device__ inline f32x4 mfma16(short8 a, short8 b, f32x4 c){
  return __builtin_amdgcn_mfma_f32_16x16x32_bf16(a, b, c, 0, 0, 0);
}

// ---------------- prep: pc [B,3,N] -> float4 [B*N] ----------------
__global__ __launch_bounds__(256) void k_prep_pts(const float* __restrict__ pc1, const float* __restrict__ pc2,
                                                  float4* __restrict__ p1, float4* __restrict__ p2){
  int i = blockIdx.x * 256 + threadIdx.x;
  if (i < NB * NPTS){
    int b = i >> 13, n = i & (NPTS - 1);
    const float* s1 = pc1 + (size_t)b * 3 * NPTS + n;
    const float* s2 = pc2 + (size_t)b * 3 * NPTS + n;
    p1[i] = make_float4(s1[0], s1[NPTS], s1[2 * NPTS], 0.f);
    p2[i] = make_float4(s2[0], s2[NPTS], s2[2 * NPTS], 0.f);
  }
}

// ---------------- transpose features [B,64,N] f32 -> [B,N,64] bf16 ----------------
__global__ __launch_bounds__(256) void k_transpose(const float* __restrict__ f1, const float* __restrict__ f2,
                                                   ushort* __restrict__ o1, ushort* __restrict__ o2){
  __shared__ ushort tile[64][257];
  int bid = blockIdx.x;
  int feat = bid >> 6; int b = (bid >> 5) & 1; int n0 = (bid & 31) * 256;
  const float* src = (feat ? f2 : f1) + (size_t)b * 64 * NPTS;
  ushort* dst = (feat ? o2 : o1) + (size_t)b * NPTS * 64;
  for (int rep = 0; rep < 64; ++rep){
    int lin = rep * 256 + threadIdx.x;
    int j = lin >> 8, nn = lin & 255;
    tile[j][nn] = f2bf(src[(size_t)j * NPTS + n0 + nn]);
  }
  __syncthreads();
  for (int rep = 0; rep < 64; ++rep){
    int lin = rep * 256 + threadIdx.x;
    int nn = lin >> 6, j = lin & 63;
    dst[(size_t)(n0 + nn) * 64 + j] = tile[j][nn];
  }
}

// ---------------- pack W0/W1 into MFMA B-fragment order (bf16) ----------------
__global__ __launch_bounds__(256) void k_packW(const float* __restrict__ W0, const float* __restrict__ W1,
                                               ushort* __restrict__ W0p, ushort* __restrict__ W1p){
  if (blockIdx.x == 0){
    for (int e = threadIdx.x; e < 8 * 5 * 64 * 8; e += 256){
      int i = e & 7, ln = (e >> 3) & 63, t = e >> 9, kt = t % 5, ct = t / 5;
      int col = ct * 16 + (ln & 15), k = kt * 32 + 8 * (ln >> 4) + i;
      W0p[e] = f2bf(k < 131 ? W0[col * 131 + k] : 0.f);
    }
  } else {
    for (int e = threadIdx.x; e < 8 * 4 * 64 * 8; e += 256){
      int i = e & 7, ln = (e >> 3) & 63, t = e >> 9, kt = t & 3, ct = t >> 2;
      int col = ct * 16 + (ln & 15), k = kt * 32 + 8 * (ln >> 4) + i;
      W1p[e] = f2bf(W1[col * 128 + k]);
    }
  }
}

// ---------------- exact KNN (fp32 top-20 scan + fp64 rerank -> top-16) ----------------
__global__ __launch_bounds__(256) void k_knn(const float4* __restrict__ qp, const float4* __restrict__ cp,
                                             int* __restrict__ outIdx){
  __shared__ float sx[4096], sy[4096], sz[4096];
  int tid = threadIdx.x, lane = tid & 63, wv = tid >> 6;
  int bid = blockIdx.x;
  int b = bid >> 8; int q0 = (bid & 255) * 32;
  int qbase = b * NPTS + q0 + wv * 8;
  float qx[8], qy[8], qz[8], sd[8], thr[8]; int si[8];
  #pragma unroll
  for (int i = 0; i < 8; ++i){
    float4 qq = qp[qbase + i];
    qx[i] = qq.x; qy[i] = qq.y; qz[i] = qq.z;
    sd[i] = 1e30f; thr[i] = 1e30f; si[i] = 0;
  }
  for (int ch = 0; ch < 2; ++ch){
    __syncthreads();
    for (int t = tid; t < 4096; t += 256){
      float4 cc = cp[b * NPTS + ch * 4096 + t];
      sx[t] = cc.x; sy[t] = cc.y; sz[t] = cc.z;
    }
    __syncthreads();
    #pragma unroll
    for (int qg = 0; qg < 2; ++qg){
      for (int it = 0; it < 64; ++it){
        float cx = sx[it * 64 + lane], cy = sy[it * 64 + lane], cz = sz[it * 64 + lane];
        int jb = ch * 4096 + it * 64;
        #pragma unroll
        for (int qi = 0; qi < 4; ++qi){
          int q = qg * 4 + qi;
          float dx = cx - qx[q], dy = cy - qy[q], dz = cz - qz[q];
          float d = fmaf(dx, dx, fmaf(dy, dy, dz * dz));
          unsigned long long m = __ballot(d < thr[q]);
          while (m){
            int src = __ffsll((unsigned long long)m) - 1;
            m &= m - 1;
            float dv = __shfl(d, src);
            if (dv >= thr[q]) continue;
            int iv = jb + src;
            float ud = __shfl_up(sd[q], 1);
            int   ui = __shfl_up(si[q], 1);
            int pos = __popcll(__ballot(sd[q] <= dv) & 0xFFFFFull);
            bool lt = lane < pos;
            bool eq = lane == pos;
            float nd = lt ? sd[q] : (eq ? dv : ud);
            int   ni = lt ? si[q] : (eq ? iv : ui);
            sd[q] = nd; si[q] = ni;
            thr[q] = __shfl(nd, KP - 1);
          }
        }
      }
    }
  }
  // fp64 rerank: keep 16 smallest of the 20
  #pragma unroll
  for (int q = 0; q < 8; ++q){
    double dd = -1.0;
    int myi = si[q];
    if (lane < KP){
      float4 cc = cp[b * NPTS + myi];
      double dx = (double)cc.x - (double)qx[q];
      double dy = (double)cc.y - (double)qy[q];
      double dz = (double)cc.z - (double)qz[q];
      dd = dx * dx + dy * dy + dz * dz;
    }
    #pragma unroll
    for (int rep = 0; rep < 4; ++rep){
      double mx = dd; int mi = lane;
      #pragma unroll
      for (int off = 32; off; off >>= 1){
        double om = __shfl_xor(mx, off);
        int oi = __shfl_xor(mi, off);
        if (om > mx || (om == mx && oi < mi)){ mx = om; mi = oi; }
      }
      if (lane == mi) dd = -1.0;
    }
    unsigned long long keep = __ballot(dd >= 0.0);
    int rank = __popcll(keep & ((1ull << lane) - 1ull));
    if (dd >= 0.0) outIdx[(size_t)(b * NPTS + q0 + wv * 8 + q) * KNN + rank] = myi;
  }
}

// ---------------- fused: gather X, MLP(131->128->128) via MFMA, wn1, k-reduce -> NF ----------------
__global__ __launch_bounds__(256) void k_fused(
    const float4* __restrict__ p1, const float4* __restrict__ p2,
    const ushort* __restrict__ f1b, const ushort* __restrict__ f2b,
    const int* __restrict__ idx1,
    const ushort* __restrict__ W0p, const ushort* __restrict__ W1p,
    const float* __restrict__ b0, const float* __restrict__ b1,
    const float* __restrict__ wn1W0, const float* __restrict__ wn1b0,
    const float* __restrict__ wn1W1, const float* __restrict__ wn1b1,
    const float* __restrict__ wn1W2, const float* __restrict__ wn1b2,
    float* __restrict__ NF)
{
  __shared__ ushort Xs[128 * LDX];     // overlaid by H after GEMM1
  __shared__ float dirS[128][4];
  __shared__ float h2S[128][8];
  __shared__ float W2s[128][8];
  __shared__ float b0S[128], b1S[128], b2S[128];
  __shared__ int idxS[128];
  int tid = threadIdx.x, lane = tid & 63, wv = tid >> 6;
  int bid = blockIdx.x;
  int b = bid >> 10; int n0 = (bid & 1023) << 3;
  int base = b * NPTS;
  for (int t = tid; t < 1024; t += 256) ((float*)W2s)[t] = wn1W2[t];
  if (tid < 128){
    b0S[tid] = b0[tid]; b1S[tid] = b1[tid]; b2S[tid] = wn1b2[tid];
    int p = tid >> 4;
    int id = idx1[(size_t)(base + n0 + p) * KNN + (tid & 15)];
    idxS[tid] = id;
    float4 c = p2[base + id];
    float4 q = p1[base + n0 + p];
    float dx = c.x - q.x, dy = c.y - q.y, dz = c.z - q.z;
    dirS[tid][0] = dx; dirS[tid][1] = dy; dirS[tid][2] = dz; dirS[tid][3] = 0.f;
    ushort* xr = Xs + tid * LDX;
    xr[128] = f2bf(dx); xr[129] = f2bf(dy); xr[130] = f2bf(dz);
    #pragma unroll
    for (int j = 131; j < 160; ++j) xr[j] = 0;
  }
  __syncthreads();
  {
    // each half-row is 64 bf16 = 128 bytes = 8 x uint4
    int r = tid >> 1, hf = tid & 1;
    const uint4* s = (const uint4*)(hf ? (f2b + (size_t)(base + idxS[r]) * 64)
                                       : (f1b + (size_t)(base + n0 + (r >> 4)) * 64));
    uint4* d = (uint4*)(Xs + r * LDX + hf * 64);
    #pragma unroll
    for (int j = 0; j < 8; ++j) d[j] = s[j];
  }
  __syncthreads();
  int r0 = wv * 32;
  f32x4 zero4 = {0.f, 0.f, 0.f, 0.f};
  f32x4 acc[2][8];
  #pragma unroll
  for (int mt = 0; mt < 2; ++mt)
    #pragma unroll
    for (int ct = 0; ct < 8; ++ct) acc[mt][ct] = zero4;
  #pragma unroll
  for (int kt = 0; kt < 5; ++kt){
    const ushort* ab = Xs + (r0 + (lane & 15)) * LDX + kt * 32 + 8 * (lane >> 4);
    short8 a0 = *(const short8*)ab;
    short8 a1 = *(const short8*)(ab + 16 * LDX);
    #pragma unroll
    for (int ct = 0; ct < 8; ++ct){
      short8 bb = *(const short8*)(W0p + (size_t)((ct * 5 + kt) * 64 + lane) * 8);
      acc[0][ct] = mfma16(a0, bb, acc[0][ct]);
      acc[1][ct] = mfma16(a1, bb, acc[1][ct]);
    }
  }
  __syncthreads();   // all X reads done; reuse as H
  ushort* Hs = Xs;
  #pragma unroll
  for (int mt = 0; mt < 2; ++mt)
    #pragma unroll
    for (int ct = 0; ct < 8; ++ct){
      int col = ct * 16 + (lane & 15);
      float bb = b0S[col];
      #pragma unroll
      for (int r = 0; r < 4; ++r){
        int row = r0 + mt * 16 + 4 * (lane >> 4) + r;
        Hs[row * LDH + col] = f2bf(leaky(acc[mt][ct][r] + bb));
      }
    }
  // wn1 hidden layers (fp32, per-row)
  if (tid < 128){
    float d0 = dirS[tid][0], d1 = dirS[tid][1], d2 = dirS[tid][2];
    float h1[8];
    #pragma unroll
    for (int i = 0; i < 8; ++i)
      h1[i] = fmaxf(fmaf(wn1W0[i * 3 + 2], d2, fmaf(wn1W0[i * 3 + 1], d1, fmaf(wn1W0[i * 3], d0, wn1b0[i]))), 0.f);
    #pragma unroll
    for (int i = 0; i < 8; ++i){
      float s = wn1b1[i];
      #pragma unroll
      for (int j = 0; j < 8; ++j) s = fmaf(wn1W1[i * 8 + j], h1[j], s);
      h2S[tid][i] = fmaxf(s, 0.f);
    }
  }
  __syncthreads();
  // GEMM2
  #pragma unroll
  for (int mt = 0; mt < 2; ++mt)
    #pragma unroll
    for (int ct = 0; ct < 8; ++ct) acc[mt][ct] = zero4;
  #pragma unroll
  for (int kt = 0; kt < 4; ++kt){
    const ushort* ab = Hs + (r0 + (lane & 15)) * LDH + kt * 32 + 8 * (lane >> 4);
    short8 a0 = *(const short8*)ab;
    short8 a1 = *(const short8*)(ab + 16 * LDH);
    #pragma unroll
    for (int ct = 0; ct < 8; ++ct){
      short8 bb = *(const short8*)(W1p + (size_t)((ct * 4 + kt) * 64 + lane) * 8);
      acc[0][ct] = mfma16(a0, bb, acc[0][ct]);
      acc[1][ct] = mfma16(a1, bb, acc[1][ct]);
    }
  }
  // epilogue: w = relu(wn1 layer3), g = leaky(acc+b1), reduce over k
  #pragma unroll
  for (int ct = 0; ct < 8; ++ct){
    int col = ct * 16 + (lane & 15);
    float4 w2a = *(const float4*)&W2s[col][0];
    float4 w2b = *(const float4*)&W2s[col][4];
    float bw = b2S[col], bg = b1S[col];
    #pragma unroll
    for (int mt = 0; mt < 2; ++mt){
      float s = 0.f;
      #pragma unroll
      for (int r = 0; r < 4; ++r){
        int row = r0 + mt * 16 + 4 * (lane >> 4) + r;
        const float4 ha = *(const float4*)&h2S[row][0];
        const float4 hb = *(const float4*)&h2S[row][4];
        float w = bw;
        w = fmaf(w2a.x, ha.x, w); w = fmaf(w2a.y, ha.y, w); w = fmaf(w2a.z, ha.z, w); w = fmaf(w2a.w, ha.w, w);
        w = fmaf(w2b.x, hb.x, w); w = fmaf(w2b.y, hb.y, w); w = fmaf(w2b.z, hb.z, w); w = fmaf(w2b.w, hb.w, w);
        w = fmaxf(w, 0.f);
        float g = leaky(acc[mt][ct][r] + bg);
        s = fmaf(w, g, s);
      }
      s += __shfl_xor(s, 16);
      s += __shfl_xor(s, 32);
      if (lane < 16) NF[(size_t)(base + n0 + wv * 2 + mt) * 128 + col] = s;
    }
  }
}

// ---------------- re-aggregation: wn2 weights + NF gather, transposed store ----------------
__global__ __launch_bounds__(256) void k_reagg(
    const float4* __restrict__ p1, const int* __restrict__ idx2,
    const float* __restrict__ NF,
    const float* __restrict__ wn2W0, const float* __restrict__ wn2b0,
    const float* __restrict__ wn2W1, const float* __restrict__ wn2b1,
    const float* __restrict__ wn2W2, const float* __restrict__ wn2b2,
    float* __restrict__ out)
{
  __shared__ float h2L[4][16][8];
  __shared__ int idxL[4][16];
  __shared__ float outT[128][20];
  int tid = threadIdx.x, lane = tid & 63, wv = tid >> 6;
  int bid = blockIdx.x;
  int b = bid >> 9; int n0 = (bid & 511) * 16;
  int base = b * NPTS;
  for (int pp = 0; pp < 4; ++pp){
    int np = wv * 4 + pp;
    int n = n0 + np;
    if (lane < 16){
      int id = idx2[(size_t)(base + n) * KNN + lane];
      idxL[wv][lane] = id;
      float4 c = p1[base + id];
      float4 q = p1[base + n];
      float d0 = c.x - q.x, d1 = c.y - q.y, d2 = c.z - q.z;
      float h1[8];
      #pragma unroll
      for (int i = 0; i < 8; ++i)
        h1[i] = fmaxf(fmaf(wn2W0[i * 3 + 2], d2, fmaf(wn2W0[i * 3 + 1], d1, fmaf(wn2W0[i * 3], d0, wn2b0[i]))), 0.f);
      #pragma unroll
      for (int i = 0; i < 8; ++i){
        float s = wn2b1[i];
        #pragma unroll
        for (int j = 0; j < 8; ++j) s = fmaf(wn2W1[i * 8 + j], h1[j], s);
        h2L[wv][lane][i] = fmaxf(s, 0.f);
      }
    }
    __syncthreads();
    #pragma unroll
    for (int hf = 0; hf < 2; ++hf){
      int c = hf * 64 + lane;
      float4 w2a = *(const float4*)(wn2W2 + c * 8);
      float4 w2b = *(const float4*)(wn2W2 + c * 8 + 4);
      float accv = 0.f, bw = wn2b2[c];
      #pragma unroll
      for (int k = 0; k < 16; ++k){
        const float4 ha = *(const float4*)&h2L[wv][k][0];
        const float4 hb = *(const float4*)&h2L[wv][k][4];
        float w = bw;
        w = fmaf(w2a.x, ha.x, w); w = fmaf(w2a.y, ha.y, w); w = fmaf(w2a.z, ha.z, w); w = fmaf(w2a.w, ha.w, w);
        w = fmaf(w2b.x, hb.x, w); w = fmaf(w2b.y, hb.y, w); w = fmaf(w2b.z, hb.z, w); w = fmaf(w2b.w, hb.w, w);
        w = fmaxf(w, 0.f);
        float g = NF[(size_t)(base + idxL[wv][k]) * 128 + c];
        accv = fmaf(w, g, accv);
      }
      outT[c][np] = accv;
    }
    __syncthreads();
  }
  {
    int c = tid >> 1, jh = (tid & 1) * 8;
    float4 v0 = *(const float4*)&outT[c][jh];
    float4 v1 = *(const float4*)&outT[c][jh + 4];
    size_t ob = ((size_t)b * 128 + c) * NPTS + n0 + jh;
    *(float4*)(out + ob) = v0;
    *(float4*)(out + ob + 4) = v1;
  }
}

extern "C" void kernel_launch(void* const* d_in, const int* in_sizes, int n_in,
                              void* d_out, int out_size, void* d_ws, size_t ws_size,
                              hipStream_t stream)
{
  const float* pc1 = (const float*)d_in[0];
  const float* pc2 = (const float*)d_in[1];
  const float* f1  = (const float*)d_in[2];
  const float* f2  = (const float*)d_in[3];
  const float* mW0 = (const float*)d_in[4];
  const float* mb0 = (const float*)d_in[5];
  const float* mW1 = (const float*)d_in[6];
  const float* mb1 = (const float*)d_in[7];
  const float* w1W0 = (const float*)d_in[8];
  const float* w1b0 = (const float*)d_in[9];
  const float* w1W1 = (const float*)d_in[10];
  const float* w1b1 = (const float*)d_in[11];
  const float* w1W2 = (const float*)d_in[12];
  const float* w1b2 = (const float*)d_in[13];
  const float* w2W0 = (const float*)d_in[14];
  const float* w2b0 = (const float*)d_in[15];
  const float* w2W1 = (const float*)d_in[16];
  const float* w2b1 = (const float*)d_in[17];
  const float* w2W2 = (const float*)d_in[18];
  const float* w2b2 = (const float*)d_in[19];

  char* ws = (char*)d_ws;
  float4* p1f4 = (float4*)(ws + 0);
  float4* p2f4 = (float4*)(ws + 262144);
  ushort* f1b  = (ushort*)(ws + 524288);
  ushort* f2b  = (ushort*)(ws + 2621440);
  int* idx1    = (int*)(ws + 4718592);
  int* idx2    = (int*)(ws + 6815744);
  ushort* W0p  = (ushort*)(ws + 8912896);
  ushort* W1p  = (ushort*)(ws + 8953856);
  float* NF    = (float*)(ws + 8986624);
  float* out   = (float*)d_out;

  hipLaunchKernelGGL(k_prep_pts, dim3(64), dim3(256), 0, stream, pc1, pc2, p1f4, p2f4);
  hipLaunchKernelGGL(k_transpose, dim3(128), dim3(256), 0, stream, f1, f2, f1b, f2b);
  hipLaunchKernelGGL(k_packW, dim3(2), dim3(256), 0, stream, mW0, mW1, W0p, W1p);
  hipLaunchKernelGGL(k_knn, dim3(512), dim3(256), 0, stream, p1f4, p2f4, idx1);
  hipLaunchKernelGGL(k_knn, dim3(512), dim3(256), 0, stream, p1f4, p1f4, idx2);
  hipLaunchKernelGGL(k_fused, dim3(2048), dim3(256), 0, stream, p1f4, p2f4, f1b, f2b, idx1,
                     W0p, W1p, mb0, mb1, w1W0, w1b0, w1W1, w1b1, w1W2, w1b2, NF);
  hipLaunchKernelGGL(k_reagg, dim3(1024), dim3(256), 0, stream, p1f4, idx2, NF,
                     w2W0, w2b0, w2W1, w2b1, w2W2, w2b2, out);
}

// Round 3
// 500.682 us; speedup vs baseline: 1.4237x; 1.4237x over previous
//
#include <hip/hip_runtime.h>

typedef __attribute__((ext_vector_type(8))) short short8;
typedef __attribute__((ext_vector_type(4))) float f32x4;

#define NPTS 8192
#define NB 2
#define KNN 16
#define KP 20
#define LDX 168
#define LDH 136

__device__ inline ushort f2bf(float x){
  unsigned u = __float_as_uint(x);
  return (ushort)((u + 0x7FFFu + ((u >> 16) & 1u)) >> 16);
}
__device__ inline float leaky(float x){ return x > 0.f ? x : 0.1f * x; }
__device__ inline f32x4 mfma16(short8 a, short8 b, f32x4 c){
  return __builtin_amdgcn_mfma_f32_16x16x32_bf16(a, b, c, 0, 0, 0);
}

// ---------------- misc: prep points (blocks 0..63) + pack W (blocks 64,65) ----------------
__global__ __launch_bounds__(256) void k_misc(const float* __restrict__ pc1, const float* __restrict__ pc2,
                                              float4* __restrict__ p1, float4* __restrict__ p2,
                                              const float* __restrict__ W0, const float* __restrict__ W1,
                                              ushort* __restrict__ W0p, ushort* __restrict__ W1p){
  int bid = blockIdx.x;
  if (bid < 64){
    int i = bid * 256 + threadIdx.x;
    int b = i >> 13, n = i & (NPTS - 1);
    const float* s1 = pc1 + (size_t)b * 3 * NPTS + n;
    const float* s2 = pc2 + (size_t)b * 3 * NPTS + n;
    p1[i] = make_float4(s1[0], s1[NPTS], s1[2 * NPTS], 0.f);
    p2[i] = make_float4(s2[0], s2[NPTS], s2[2 * NPTS], 0.f);
  } else if (bid == 64){
    for (int e = threadIdx.x; e < 8 * 5 * 64 * 8; e += 256){
      int i = e & 7, ln = (e >> 3) & 63, t = e >> 9, kt = t % 5, ct = t / 5;
      int col = ct * 16 + (ln & 15), k = kt * 32 + 8 * (ln >> 4) + i;
      W0p[e] = f2bf(k < 131 ? W0[col * 131 + k] : 0.f);
    }
  } else {
    for (int e = threadIdx.x; e < 8 * 4 * 64 * 8; e += 256){
      int i = e & 7, ln = (e >> 3) & 63, t = e >> 9, kt = t & 3, ct = t >> 2;
      int col = ct * 16 + (ln & 15), k = kt * 32 + 8 * (ln >> 4) + i;
      W1p[e] = f2bf(W1[col * 128 + k]);
    }
  }
}

// ---------------- transpose features [B,64,N] f32 -> [B,N,64] bf16 ----------------
__global__ __launch_bounds__(256) void k_transpose(const float* __restrict__ f1, const float* __restrict__ f2,
                                                   ushort* __restrict__ o1, ushort* __restrict__ o2){
  __shared__ ushort tile[64][257];
  int bid = blockIdx.x;
  int feat = bid >> 6; int b = (bid >> 5) & 1; int n0 = (bid & 31) * 256;
  const float* src = (feat ? f2 : f1) + (size_t)b * 64 * NPTS;
  ushort* dst = (feat ? o2 : o1) + (size_t)b * NPTS * 64;
  for (int rep = 0; rep < 64; ++rep){
    int lin = rep * 256 + threadIdx.x;
    int j = lin >> 8, nn = lin & 255;
    tile[j][nn] = f2bf(src[(size_t)j * NPTS + n0 + nn]);
  }
  __syncthreads();
  for (int rep = 0; rep < 64; ++rep){
    int lin = rep * 256 + threadIdx.x;
    int nn = lin >> 6, j = lin & 63;
    dst[(size_t)(n0 + nn) * 64 + j] = tile[j][nn];
  }
}

// ---------------- exact KNN, both tasks in one launch ----------------
// task 0: q=p1, c=p2 -> idx1 ; task 1: q=p1, c=p1 -> idx2
// 4 queries per wave, 16 per block; candidates staged in 4 chunks of 2048 (24KB LDS)
__global__ __launch_bounds__(256) void k_knn(const float4* __restrict__ p1, const float4* __restrict__ p2,
                                             int* __restrict__ idx1, int* __restrict__ idx2){
  __shared__ float sx[2048], sy[2048], sz[2048];
  int tid = threadIdx.x, lane = tid & 63, wv = tid >> 6;
  int bid = blockIdx.x;
  int task = bid >> 10, rem = bid & 1023;
  int b = rem >> 9; int q0 = (rem & 511) * 16;
  const float4* __restrict__ cp = task ? p1 : p2;
  int* __restrict__ outIdx = task ? idx2 : idx1;
  int qbase = b * NPTS + q0 + wv * 4;
  float qx[4], qy[4], qz[4], sd[4], thr[4]; int si[4];
  #pragma unroll
  for (int i = 0; i < 4; ++i){
    float4 qq = p1[qbase + i];
    qx[i] = qq.x; qy[i] = qq.y; qz[i] = qq.z;
    sd[i] = 1e30f; thr[i] = 1e30f; si[i] = 0;
  }
  for (int ch = 0; ch < 4; ++ch){
    __syncthreads();
    for (int t = tid; t < 2048; t += 256){
      float4 cc = cp[b * NPTS + ch * 2048 + t];
      sx[t] = cc.x; sy[t] = cc.y; sz[t] = cc.z;
    }
    __syncthreads();
    for (int it = 0; it < 32; ++it){
      float cx = sx[it * 64 + lane], cy = sy[it * 64 + lane], cz = sz[it * 64 + lane];
      int jb = ch * 2048 + it * 64;
      #pragma unroll
      for (int q = 0; q < 4; ++q){
        float dx = cx - qx[q], dy = cy - qy[q], dz = cz - qz[q];
        float d = fmaf(dx, dx, fmaf(dy, dy, dz * dz));
        unsigned long long m = __ballot(d < thr[q]);
        while (m){
          int src = __ffsll((unsigned long long)m) - 1;
          m &= m - 1;
          float dv = __shfl(d, src);
          if (dv >= thr[q]) continue;
          int iv = jb + src;
          float ud = __shfl_up(sd[q], 1);
          int   ui = __shfl_up(si[q], 1);
          int pos = __popcll(__ballot(sd[q] <= dv) & 0xFFFFFull);
          bool lt = lane < pos;
          bool eq = lane == pos;
          float nd = lt ? sd[q] : (eq ? dv : ud);
          int   ni = lt ? si[q] : (eq ? iv : ui);
          sd[q] = nd; si[q] = ni;
          thr[q] = __shfl(nd, KP - 1);
        }
      }
    }
  }
  // fp64 rerank: keep 16 smallest of the 20
  #pragma unroll
  for (int q = 0; q < 4; ++q){
    double dd = -1.0;
    int myi = si[q];
    if (lane < KP){
      float4 cc = cp[b * NPTS + myi];
      double dx = (double)cc.x - (double)qx[q];
      double dy = (double)cc.y - (double)qy[q];
      double dz = (double)cc.z - (double)qz[q];
      dd = dx * dx + dy * dy + dz * dz;
    }
    #pragma unroll
    for (int rep = 0; rep < 4; ++rep){
      double mx = dd; int mi = lane;
      #pragma unroll
      for (int off = 32; off; off >>= 1){
        double om = __shfl_xor(mx, off);
        int oi = __shfl_xor(mi, off);
        if (om > mx || (om == mx && oi < mi)){ mx = om; mi = oi; }
      }
      if (lane == mi) dd = -1.0;
    }
    unsigned long long keep = __ballot(dd >= 0.0);
    int rank = __popcll(keep & ((1ull << lane) - 1ull));
    if (dd >= 0.0) outIdx[(size_t)(b * NPTS + q0 + wv * 4 + q) * KNN + rank] = myi;
  }
}

// ---------------- fused: gather X, MLP(131->128->128) via MFMA, wn1, k-reduce -> NF ----------------
__global__ __launch_bounds__(256) void k_fused(
    const float4* __restrict__ p1, const float4* __restrict__ p2,
    const ushort* __restrict__ f1b, const ushort* __restrict__ f2b,
    const int* __restrict__ idx1,
    const ushort* __restrict__ W0p, const ushort* __restrict__ W1p,
    const float* __restrict__ b0, const float* __restrict__ b1,
    const float* __restrict__ wn1W0, const float* __restrict__ wn1b0,
    const float* __restrict__ wn1W1, const float* __restrict__ wn1b1,
    const float* __restrict__ wn1W2, const float* __restrict__ wn1b2,
    float* __restrict__ NF)
{
  __shared__ ushort Xs[128 * LDX];     // overlaid by H after GEMM1
  __shared__ float dirS[128][4];
  __shared__ float h2S[128][8];
  __shared__ float W2s[128][8];
  __shared__ float b0S[128], b1S[128], b2S[128];
  __shared__ int idxS[128];
  int tid = threadIdx.x, lane = tid & 63, wv = tid >> 6;
  int bid = blockIdx.x;
  int b = bid >> 10; int n0 = (bid & 1023) << 3;
  int base = b * NPTS;
  for (int t = tid; t < 1024; t += 256) ((float*)W2s)[t] = wn1W2[t];
  if (tid < 128){
    b0S[tid] = b0[tid]; b1S[tid] = b1[tid]; b2S[tid] = wn1b2[tid];
    int p = tid >> 4;
    int id = idx1[(size_t)(base + n0 + p) * KNN + (tid & 15)];
    idxS[tid] = id;
    float4 c = p2[base + id];
    float4 q = p1[base + n0 + p];
    float dx = c.x - q.x, dy = c.y - q.y, dz = c.z - q.z;
    dirS[tid][0] = dx; dirS[tid][1] = dy; dirS[tid][2] = dz; dirS[tid][3] = 0.f;
    ushort* xr = Xs + tid * LDX;
    xr[128] = f2bf(dx); xr[129] = f2bf(dy); xr[130] = f2bf(dz);
    #pragma unroll
    for (int j = 131; j < 160; ++j) xr[j] = 0;
  }
  __syncthreads();
  {
    // each half-row is 64 bf16 = 128 bytes = 8 x uint4
    int r = tid >> 1, hf = tid & 1;
    const uint4* s = (const uint4*)(hf ? (f2b + (size_t)(base + idxS[r]) * 64)
                                       : (f1b + (size_t)(base + n0 + (r >> 4)) * 64));
    uint4* d = (uint4*)(Xs + r * LDX + hf * 64);
    #pragma unroll
    for (int j = 0; j < 8; ++j) d[j] = s[j];
  }
  __syncthreads();
  int r0 = wv * 32;
  f32x4 zero4 = {0.f, 0.f, 0.f, 0.f};
  f32x4 acc[2][8];
  #pragma unroll
  for (int mt = 0; mt < 2; ++mt)
    #pragma unroll
    for (int ct = 0; ct < 8; ++ct) acc[mt][ct] = zero4;
  #pragma unroll
  for (int kt = 0; kt < 5; ++kt){
    const ushort* ab = Xs + (r0 + (lane & 15)) * LDX + kt * 32 + 8 * (lane >> 4);
    short8 a0 = *(const short8*)ab;
    short8 a1 = *(const short8*)(ab + 16 * LDX);
    #pragma unroll
    for (int ct = 0; ct < 8; ++ct){
      short8 bb = *(const short8*)(W0p + (size_t)((ct * 5 + kt) * 64 + lane) * 8);
      acc[0][ct] = mfma16(a0, bb, acc[0][ct]);
      acc[1][ct] = mfma16(a1, bb, acc[1][ct]);
    }
  }
  __syncthreads();   // all X reads done; reuse as H
  ushort* Hs = Xs;
  #pragma unroll
  for (int mt = 0; mt < 2; ++mt)
    #pragma unroll
    for (int ct = 0; ct < 8; ++ct){
      int col = ct * 16 + (lane & 15);
      float bb = b0S[col];
      #pragma unroll
      for (int r = 0; r < 4; ++r){
        int row = r0 + mt * 16 + 4 * (lane >> 4) + r;
        Hs[row * LDH + col] = f2bf(leaky(acc[mt][ct][r] + bb));
      }
    }
  // wn1 hidden layers (fp32, per-row)
  if (tid < 128){
    float d0 = dirS[tid][0], d1 = dirS[tid][1], d2 = dirS[tid][2];
    float h1[8];
    #pragma unroll
    for (int i = 0; i < 8; ++i)
      h1[i] = fmaxf(fmaf(wn1W0[i * 3 + 2], d2, fmaf(wn1W0[i * 3 + 1], d1, fmaf(wn1W0[i * 3], d0, wn1b0[i]))), 0.f);
    #pragma unroll
    for (int i = 0; i < 8; ++i){
      float s = wn1b1[i];
      #pragma unroll
      for (int j = 0; j < 8; ++j) s = fmaf(wn1W1[i * 8 + j], h1[j], s);
      h2S[tid][i] = fmaxf(s, 0.f);
    }
  }
  __syncthreads();
  // GEMM2
  #pragma unroll
  for (int mt = 0; mt < 2; ++mt)
    #pragma unroll
    for (int ct = 0; ct < 8; ++ct) acc[mt][ct] = zero4;
  #pragma unroll
  for (int kt = 0; kt < 4; ++kt){
    const ushort* ab = Hs + (r0 + (lane & 15)) * LDH + kt * 32 + 8 * (lane >> 4);
    short8 a0 = *(const short8*)ab;
    short8 a1 = *(const short8*)(ab + 16 * LDH);
    #pragma unroll
    for (int ct = 0; ct < 8; ++ct){
      short8 bb = *(const short8*)(W1p + (size_t)((ct * 4 + kt) * 64 + lane) * 8);
      acc[0][ct] = mfma16(a0, bb, acc[0][ct]);
      acc[1][ct] = mfma16(a1, bb, acc[1][ct]);
    }
  }
  // epilogue: w = relu(wn1 layer3), g = leaky(acc+b1), reduce over k
  #pragma unroll
  for (int ct = 0; ct < 8; ++ct){
    int col = ct * 16 + (lane & 15);
    float4 w2a = *(const float4*)&W2s[col][0];
    float4 w2b = *(const float4*)&W2s[col][4];
    float bw = b2S[col], bg = b1S[col];
    #pragma unroll
    for (int mt = 0; mt < 2; ++mt){
      float s = 0.f;
      #pragma unroll
      for (int r = 0; r < 4; ++r){
        int row = r0 + mt * 16 + 4 * (lane >> 4) + r;
        const float4 ha = *(const float4*)&h2S[row][0];
        const float4 hb = *(const float4*)&h2S[row][4];
        float w = bw;
        w = fmaf(w2a.x, ha.x, w); w = fmaf(w2a.y, ha.y, w); w = fmaf(w2a.z, ha.z, w); w = fmaf(w2a.w, ha.w, w);
        w = fmaf(w2b.x, hb.x, w); w = fmaf(w2b.y, hb.y, w); w = fmaf(w2b.z, hb.z, w); w = fmaf(w2b.w, hb.w, w);
        w = fmaxf(w, 0.f);
        float g = leaky(acc[mt][ct][r] + bg);
        s = fmaf(w, g, s);
      }
      s += __shfl_xor(s, 16);
      s += __shfl_xor(s, 32);
      if (lane < 16) NF[(size_t)(base + n0 + wv * 2 + mt) * 128 + col] = s;
    }
  }
}

// ---------------- re-aggregation: wn2 weights + NF gather, transposed store ----------------
__global__ __launch_bounds__(256) void k_reagg(
    const float4* __restrict__ p1, const int* __restrict__ idx2,
    const float* __restrict__ NF,
    const float* __restrict__ wn2W0, const float* __restrict__ wn2b0,
    const float* __restrict__ wn2W1, const float* __restrict__ wn2b1,
    const float* __restrict__ wn2W2, const float* __restrict__ wn2b2,
    float* __restrict__ out)
{
  __shared__ float h2L[4][16][8];
  __shared__ int idxL[4][16];
  __shared__ float outT[128][20];
  int tid = threadIdx.x, lane = tid & 63, wv = tid >> 6;
  int bid = blockIdx.x;
  int b = bid >> 9; int n0 = (bid & 511) * 16;
  int base = b * NPTS;
  for (int pp = 0; pp < 4; ++pp){
    int np = wv * 4 + pp;
    int n = n0 + np;
    if (lane < 16){
      int id = idx2[(size_t)(base + n) * KNN + lane];
      idxL[wv][lane] = id;
      float4 c = p1[base + id];
      float4 q = p1[base + n];
      float d0 = c.x - q.x, d1 = c.y - q.y, d2 = c.z - q.z;
      float h1[8];
      #pragma unroll
      for (int i = 0; i < 8; ++i)
        h1[i] = fmaxf(fmaf(wn2W0[i * 3 + 2], d2, fmaf(wn2W0[i * 3 + 1], d1, fmaf(wn2W0[i * 3], d0, wn2b0[i]))), 0.f);
      #pragma unroll
      for (int i = 0; i < 8; ++i){
        float s = wn2b1[i];
        #pragma unroll
        for (int j = 0; j < 8; ++j) s = fmaf(wn2W1[i * 8 + j], h1[j], s);
        h2L[wv][lane][i] = fmaxf(s, 0.f);
      }
    }
    __syncthreads();
    #pragma unroll
    for (int hf = 0; hf < 2; ++hf){
      int c = hf * 64 + lane;
      float4 w2a = *(const float4*)(wn2W2 + c * 8);
      float4 w2b = *(const float4*)(wn2W2 + c * 8 + 4);
      float accv = 0.f, bw = wn2b2[c];
      #pragma unroll
      for (int k = 0; k < 16; ++k){
        const float4 ha = *(const float4*)&h2L[wv][k][0];
        const float4 hb = *(const float4*)&h2L[wv][k][4];
        float w = bw;
        w = fmaf(w2a.x, ha.x, w); w = fmaf(w2a.y, ha.y, w); w = fmaf(w2a.z, ha.z, w); w = fmaf(w2a.w, ha.w, w);
        w = fmaf(w2b.x, hb.x, w); w = fmaf(w2b.y, hb.y, w); w = fmaf(w2b.z, hb.z, w); w = fmaf(w2b.w, hb.w, w);
        w = fmaxf(w, 0.f);
        float g = NF[(size_t)(base + idxL[wv][k]) * 128 + c];
        accv = fmaf(w, g, accv);
      }
      outT[c][np] = accv;
    }
    __syncthreads();
  }
  {
    int c = tid >> 1, jh = (tid & 1) * 8;
    float4 v0 = *(const float4*)&outT[c][jh];
    float4 v1 = *(const float4*)&outT[c][jh + 4];
    size_t ob = ((size_t)b * 128 + c) * NPTS + n0 + jh;
    *(float4*)(out + ob) = v0;
    *(float4*)(out + ob + 4) = v1;
  }
}

extern "C" void kernel_launch(void* const* d_in, const int* in_sizes, int n_in,
                              void* d_out, int out_size, void* d_ws, size_t ws_size,
                              hipStream_t stream)
{
  const float* pc1 = (const float*)d_in[0];
  const float* pc2 = (const float*)d_in[1];
  const float* f1  = (const float*)d_in[2];
  const float* f2  = (const float*)d_in[3];
  const float* mW0 = (const float*)d_in[4];
  const float* mb0 = (const float*)d_in[5];
  const float* mW1 = (const float*)d_in[6];
  const float* mb1 = (const float*)d_in[7];
  const float* w1W0 = (const float*)d_in[8];
  const float* w1b0 = (const float*)d_in[9];
  const float* w1W1 = (const float*)d_in[10];
  const float* w1b1 = (const float*)d_in[11];
  const float* w1W2 = (const float*)d_in[12];
  const float* w1b2 = (const float*)d_in[13];
  const float* w2W0 = (const float*)d_in[14];
  const float* w2b0 = (const float*)d_in[15];
  const float* w2W1 = (const float*)d_in[16];
  const float* w2b1 = (const float*)d_in[17];
  const float* w2W2 = (const float*)d_in[18];
  const float* w2b2 = (const float*)d_in[19];

  char* ws = (char*)d_ws;
  float4* p1f4 = (float4*)(ws + 0);
  float4* p2f4 = (float4*)(ws + 262144);
  ushort* f1b  = (ushort*)(ws + 524288);
  ushort* f2b  = (ushort*)(ws + 2621440);
  int* idx1    = (int*)(ws + 4718592);
  int* idx2    = (int*)(ws + 6815744);
  ushort* W0p  = (ushort*)(ws + 8912896);
  ushort* W1p  = (ushort*)(ws + 8953856);
  float* NF    = (float*)(ws + 8986624);
  float* out   = (float*)d_out;

  hipLaunchKernelGGL(k_misc, dim3(66), dim3(256), 0, stream, pc1, pc2, p1f4, p2f4, mW0, mW1, W0p, W1p);
  hipLaunchKernelGGL(k_transpose, dim3(128), dim3(256), 0, stream, f1, f2, f1b, f2b);
  hipLaunchKernelGGL(k_knn, dim3(2048), dim3(256), 0, stream, p1f4, p2f4, idx1, idx2);
  hipLaunchKernelGGL(k_fused, dim3(2048), dim3(256), 0, stream, p1f4, p2f4, f1b, f2b, idx1,
                     W0p, W1p, mb0, mb1, w1W0, w1b0, w1W1, w1b1, w1W2, w1b2, NF);
  hipLaunchKernelGGL(k_reagg, dim3(1024), dim3(256), 0, stream, p1f4, idx2, NF,
                     w2W0, w2b0, w2W1, w2b1, w2W2, w2b2, out);
}

// Round 4
// 493.206 us; speedup vs baseline: 1.4453x; 1.0152x over previous
//
#include <hip/hip_runtime.h>

typedef __attribute__((ext_vector_type(8))) short short8;
typedef __attribute__((ext_vector_type(4))) float f32x4;

#define NPTS 8192
#define NB 2
#define KNN 16
#define KP 20
#define LDX 168
#define LDH 136

__device__ inline ushort f2bf(float x){
  unsigned u = __float_as_uint(x);
  return (ushort)((u + 0x7FFFu + ((u >> 16) & 1u)) >> 16);
}
__device__ inline float leaky(float x){ return x > 0.f ? x : 0.1f * x; }
__device__ inline f32x4 mfma16(short8 a, short8 b, f32x4 c){
  return __builtin_amdgcn_mfma_f32_16x16x32_bf16(a, b, c, 0, 0, 0);
}

// ---------------- misc: prep points (blocks 0..63) + pack W (blocks 64,65) ----------------
__global__ __launch_bounds__(256) void k_misc(const float* __restrict__ pc1, const float* __restrict__ pc2,
                                              float4* __restrict__ p1, float4* __restrict__ p2,
                                              const float* __restrict__ W0, const float* __restrict__ W1,
                                              ushort* __restrict__ W0p, ushort* __restrict__ W1p){
  int bid = blockIdx.x;
  if (bid < 64){
    int i = bid * 256 + threadIdx.x;
    int b = i >> 13, n = i & (NPTS - 1);
    const float* s1 = pc1 + (size_t)b * 3 * NPTS + n;
    const float* s2 = pc2 + (size_t)b * 3 * NPTS + n;
    p1[i] = make_float4(s1[0], s1[NPTS], s1[2 * NPTS], 0.f);
    p2[i] = make_float4(s2[0], s2[NPTS], s2[2 * NPTS], 0.f);
  } else if (bid == 64){
    for (int e = threadIdx.x; e < 8 * 5 * 64 * 8; e += 256){
      int i = e & 7, ln = (e >> 3) & 63, t = e >> 9, kt = t % 5, ct = t / 5;
      int col = ct * 16 + (ln & 15), k = kt * 32 + 8 * (ln >> 4) + i;
      W0p[e] = f2bf(k < 131 ? W0[col * 131 + k] : 0.f);
    }
  } else {
    for (int e = threadIdx.x; e < 8 * 4 * 64 * 8; e += 256){
      int i = e & 7, ln = (e >> 3) & 63, t = e >> 9, kt = t & 3, ct = t >> 2;
      int col = ct * 16 + (ln & 15), k = kt * 32 + 8 * (ln >> 4) + i;
      W1p[e] = f2bf(W1[col * 128 + k]);
    }
  }
}

// ---------------- transpose features [B,64,N] f32 -> [B,N,64] bf16 ----------------
__global__ __launch_bounds__(256) void k_transpose(const float* __restrict__ f1, const float* __restrict__ f2,
                                                   ushort* __restrict__ o1, ushort* __restrict__ o2){
  __shared__ ushort tile[64][257];
  int bid = blockIdx.x;
  int feat = bid >> 6; int b = (bid >> 5) & 1; int n0 = (bid & 31) * 256;
  const float* src = (feat ? f2 : f1) + (size_t)b * 64 * NPTS;
  ushort* dst = (feat ? o2 : o1) + (size_t)b * NPTS * 64;
  for (int rep = 0; rep < 64; ++rep){
    int lin = rep * 256 + threadIdx.x;
    int j = lin >> 8, nn = lin & 255;
    tile[j][nn] = f2bf(src[(size_t)j * NPTS + n0 + nn]);
  }
  __syncthreads();
  for (int rep = 0; rep < 64; ++rep){
    int lin = rep * 256 + threadIdx.x;
    int nn = lin >> 6, j = lin & 63;
    dst[(size_t)(n0 + nn) * 64 + j] = tile[j][nn];
  }
}

// ---------------- exact KNN, both tasks in one launch ----------------
// task 0: q=p1, c=p2 -> idx1 ; task 1: q=p1, c=p1 -> idx2
// 4 queries per wave, 16 per block; candidates staged in 8 chunks of 1024 (12KB LDS -> full occupancy)
__global__ __launch_bounds__(256) void k_knn(const float4* __restrict__ p1, const float4* __restrict__ p2,
                                             int* __restrict__ idx1, int* __restrict__ idx2){
  __shared__ float sx[1024], sy[1024], sz[1024];
  int tid = threadIdx.x, lane = tid & 63, wv = tid >> 6;
  int bid = blockIdx.x;
  int task = bid >> 10, rem = bid & 1023;
  int b = rem >> 9; int q0 = (rem & 511) * 16;
  const float4* __restrict__ cp = task ? p1 : p2;
  int* __restrict__ outIdx = task ? idx2 : idx1;
  int qbase = b * NPTS + q0 + wv * 4;
  float qx[4], qy[4], qz[4], sd[4], thr[4]; int si[4];
  #pragma unroll
  for (int i = 0; i < 4; ++i){
    float4 qq = p1[qbase + i];
    qx[i] = qq.x; qy[i] = qq.y; qz[i] = qq.z;
    sd[i] = 1e30f; thr[i] = 1e30f; si[i] = 0;
  }
  for (int ch = 0; ch < 8; ++ch){
    __syncthreads();
    for (int t = tid; t < 1024; t += 256){
      float4 cc = cp[b * NPTS + ch * 1024 + t];
      sx[t] = cc.x; sy[t] = cc.y; sz[t] = cc.z;
    }
    __syncthreads();
    for (int it = 0; it < 16; ++it){
      float cx = sx[it * 64 + lane], cy = sy[it * 64 + lane], cz = sz[it * 64 + lane];
      int jb = ch * 1024 + it * 64;
      #pragma unroll
      for (int q = 0; q < 4; ++q){
        float dx = cx - qx[q], dy = cy - qy[q], dz = cz - qz[q];
        float d = fmaf(dx, dx, fmaf(dy, dy, dz * dz));
        unsigned long long m = __ballot(d < thr[q]);
        while (m){
          int src = __ffsll((unsigned long long)m) - 1;
          m &= m - 1;
          float dv = __shfl(d, src);
          if (dv >= thr[q]) continue;
          int iv = jb + src;
          float ud = __shfl_up(sd[q], 1);
          int   ui = __shfl_up(si[q], 1);
          int pos = __popcll(__ballot(sd[q] <= dv) & 0xFFFFFull);
          bool lt = lane < pos;
          bool eq = lane == pos;
          float nd = lt ? sd[q] : (eq ? dv : ud);
          int   ni = lt ? si[q] : (eq ? iv : ui);
          sd[q] = nd; si[q] = ni;
          thr[q] = __shfl(nd, KP - 1);
        }
      }
    }
  }
  // fp64 rerank: keep 16 smallest of the 20
  #pragma unroll
  for (int q = 0; q < 4; ++q){
    double dd = -1.0;
    int myi = si[q];
    if (lane < KP){
      float4 cc = cp[b * NPTS + myi];
      double dx = (double)cc.x - (double)qx[q];
      double dy = (double)cc.y - (double)qy[q];
      double dz = (double)cc.z - (double)qz[q];
      dd = dx * dx + dy * dy + dz * dz;
    }
    #pragma unroll
    for (int rep = 0; rep < 4; ++rep){
      double mx = dd; int mi = lane;
      #pragma unroll
      for (int off = 32; off; off >>= 1){
        double om = __shfl_xor(mx, off);
        int oi = __shfl_xor(mi, off);
        if (om > mx || (om == mx && oi < mi)){ mx = om; mi = oi; }
      }
      if (lane == mi) dd = -1.0;
    }
    unsigned long long keep = __ballot(dd >= 0.0);
    int rank = __popcll(keep & ((1ull << lane) - 1ull));
    if (dd >= 0.0) outIdx[(size_t)(b * NPTS + q0 + wv * 4 + q) * KNN + rank] = myi;
  }
}

// ---------------- fused: gather X, MLP(131->128->128) via MFMA, wn1, k-reduce -> NF ----------------
__global__ __launch_bounds__(256) void k_fused(
    const float4* __restrict__ p1, const float4* __restrict__ p2,
    const ushort* __restrict__ f1b, const ushort* __restrict__ f2b,
    const int* __restrict__ idx1,
    const ushort* __restrict__ W0p, const ushort* __restrict__ W1p,
    const float* __restrict__ b0, const float* __restrict__ b1,
    const float* __restrict__ wn1W0, const float* __restrict__ wn1b0,
    const float* __restrict__ wn1W1, const float* __restrict__ wn1b1,
    const float* __restrict__ wn1W2, const float* __restrict__ wn1b2,
    float* __restrict__ NF)
{
  __shared__ ushort Xs[128 * LDX];     // overlaid by H after GEMM1
  __shared__ float dirS[128][4];
  __shared__ float h2S[128][8];
  __shared__ float W2s[128][8];
  __shared__ float b0S[128], b1S[128], b2S[128];
  __shared__ int idxS[128];
  int tid = threadIdx.x, lane = tid & 63, wv = tid >> 6;
  int bid = blockIdx.x;
  int b = bid >> 10; int n0 = (bid & 1023) << 3;
  int base = b * NPTS;
  for (int t = tid; t < 1024; t += 256) ((float*)W2s)[t] = wn1W2[t];
  if (tid < 128){
    b0S[tid] = b0[tid]; b1S[tid] = b1[tid]; b2S[tid] = wn1b2[tid];
    int p = tid >> 4;
    int id = idx1[(size_t)(base + n0 + p) * KNN + (tid & 15)];
    idxS[tid] = id;
    float4 c = p2[base + id];
    float4 q = p1[base + n0 + p];
    float dx = c.x - q.x, dy = c.y - q.y, dz = c.z - q.z;
    dirS[tid][0] = dx; dirS[tid][1] = dy; dirS[tid][2] = dz; dirS[tid][3] = 0.f;
    ushort* xr = Xs + tid * LDX;
    xr[128] = f2bf(dx); xr[129] = f2bf(dy); xr[130] = f2bf(dz);
    #pragma unroll
    for (int j = 131; j < 160; ++j) xr[j] = 0;
  }
  __syncthreads();
  {
    // each half-row is 64 bf16 = 128 bytes = 8 x uint4
    int r = tid >> 1, hf = tid & 1;
    const uint4* s = (const uint4*)(hf ? (f2b + (size_t)(base + idxS[r]) * 64)
                                       : (f1b + (size_t)(base + n0 + (r >> 4)) * 64));
    uint4* d = (uint4*)(Xs + r * LDX + hf * 64);
    #pragma unroll
    for (int j = 0; j < 8; ++j) d[j] = s[j];
  }
  __syncthreads();
  int r0 = wv * 32;
  f32x4 zero4 = {0.f, 0.f, 0.f, 0.f};
  f32x4 acc[2][8];
  #pragma unroll
  for (int mt = 0; mt < 2; ++mt)
    #pragma unroll
    for (int ct = 0; ct < 8; ++ct) acc[mt][ct] = zero4;
  #pragma unroll
  for (int kt = 0; kt < 5; ++kt){
    const ushort* ab = Xs + (r0 + (lane & 15)) * LDX + kt * 32 + 8 * (lane >> 4);
    short8 a0 = *(const short8*)ab;
    short8 a1 = *(const short8*)(ab + 16 * LDX);
    #pragma unroll
    for (int ct = 0; ct < 8; ++ct){
      short8 bb = *(const short8*)(W0p + (size_t)((ct * 5 + kt) * 64 + lane) * 8);
      acc[0][ct] = mfma16(a0, bb, acc[0][ct]);
      acc[1][ct] = mfma16(a1, bb, acc[1][ct]);
    }
  }
  __syncthreads();   // all X reads done; reuse as H
  ushort* Hs = Xs;
  #pragma unroll
  for (int mt = 0; mt < 2; ++mt)
    #pragma unroll
    for (int ct = 0; ct < 8; ++ct){
      int col = ct * 16 + (lane & 15);
      float bb = b0S[col];
      #pragma unroll
      for (int r = 0; r < 4; ++r){
        int row = r0 + mt * 16 + 4 * (lane >> 4) + r;
        Hs[row * LDH + col] = f2bf(leaky(acc[mt][ct][r] + bb));
      }
    }
  // wn1 hidden layers (fp32, per-row)
  if (tid < 128){
    float d0 = dirS[tid][0], d1 = dirS[tid][1], d2 = dirS[tid][2];
    float h1[8];
    #pragma unroll
    for (int i = 0; i < 8; ++i)
      h1[i] = fmaxf(fmaf(wn1W0[i * 3 + 2], d2, fmaf(wn1W0[i * 3 + 1], d1, fmaf(wn1W0[i * 3], d0, wn1b0[i]))), 0.f);
    #pragma unroll
    for (int i = 0; i < 8; ++i){
      float s = wn1b1[i];
      #pragma unroll
      for (int j = 0; j < 8; ++j) s = fmaf(wn1W1[i * 8 + j], h1[j], s);
      h2S[tid][i] = fmaxf(s, 0.f);
    }
  }
  __syncthreads();
  // GEMM2
  #pragma unroll
  for (int mt = 0; mt < 2; ++mt)
    #pragma unroll
    for (int ct = 0; ct < 8; ++ct) acc[mt][ct] = zero4;
  #pragma unroll
  for (int kt = 0; kt < 4; ++kt){
    const ushort* ab = Hs + (r0 + (lane & 15)) * LDH + kt * 32 + 8 * (lane >> 4);
    short8 a0 = *(const short8*)ab;
    short8 a1 = *(const short8*)(ab + 16 * LDH);
    #pragma unroll
    for (int ct = 0; ct < 8; ++ct){
      short8 bb = *(const short8*)(W1p + (size_t)((ct * 4 + kt) * 64 + lane) * 8);
      acc[0][ct] = mfma16(a0, bb, acc[0][ct]);
      acc[1][ct] = mfma16(a1, bb, acc[1][ct]);
    }
  }
  // epilogue: w = relu(wn1 layer3), g = leaky(acc+b1), reduce over k
  #pragma unroll
  for (int ct = 0; ct < 8; ++ct){
    int col = ct * 16 + (lane & 15);
    float4 w2a = *(const float4*)&W2s[col][0];
    float4 w2b = *(const float4*)&W2s[col][4];
    float bw = b2S[col], bg = b1S[col];
    #pragma unroll
    for (int mt = 0; mt < 2; ++mt){
      float s = 0.f;
      #pragma unroll
      for (int r = 0; r < 4; ++r){
        int row = r0 + mt * 16 + 4 * (lane >> 4) + r;
        const float4 ha = *(const float4*)&h2S[row][0];
        const float4 hb = *(const float4*)&h2S[row][4];
        float w = bw;
        w = fmaf(w2a.x, ha.x, w); w = fmaf(w2a.y, ha.y, w); w = fmaf(w2a.z, ha.z, w); w = fmaf(w2a.w, ha.w, w);
        w = fmaf(w2b.x, hb.x, w); w = fmaf(w2b.y, hb.y, w); w = fmaf(w2b.z, hb.z, w); w = fmaf(w2b.w, hb.w, w);
        w = fmaxf(w, 0.f);
        float g = leaky(acc[mt][ct][r] + bg);
        s = fmaf(w, g, s);
      }
      s += __shfl_xor(s, 16);
      s += __shfl_xor(s, 32);
      if (lane < 16) NF[(size_t)(base + n0 + wv * 2 + mt) * 128 + col] = s;
    }
  }
}

// ---------------- re-aggregation: wn2 weights + NF gather, transposed store ----------------
__global__ __launch_bounds__(256) void k_reagg(
    const float4* __restrict__ p1, const int* __restrict__ idx2,
    const float* __restrict__ NF,
    const float* __restrict__ wn2W0, const float* __restrict__ wn2b0,
    const float* __restrict__ wn2W1, const float* __restrict__ wn2b1,
    const float* __restrict__ wn2W2, const float* __restrict__ wn2b2,
    float* __restrict__ out)
{
  __shared__ float h2L[4][16][8];
  __shared__ int idxL[4][16];
  __shared__ float outT[128][20];
  int tid = threadIdx.x, lane = tid & 63, wv = tid >> 6;
  int bid = blockIdx.x;
  int b = bid >> 9; int n0 = (bid & 511) * 16;
  int base = b * NPTS;
  for (int pp = 0; pp < 4; ++pp){
    int np = wv * 4 + pp;
    int n = n0 + np;
    if (lane < 16){
      int id = idx2[(size_t)(base + n) * KNN + lane];
      idxL[wv][lane] = id;
      float4 c = p1[base + id];
      float4 q = p1[base + n];
      float d0 = c.x - q.x, d1 = c.y - q.y, d2 = c.z - q.z;
      float h1[8];
      #pragma unroll
      for (int i = 0; i < 8; ++i)
        h1[i] = fmaxf(fmaf(wn2W0[i * 3 + 2], d2, fmaf(wn2W0[i * 3 + 1], d1, fmaf(wn2W0[i * 3], d0, wn2b0[i]))), 0.f);
      #pragma unroll
      for (int i = 0; i < 8; ++i){
        float s = wn2b1[i];
        #pragma unroll
        for (int j = 0; j < 8; ++j) s = fmaf(wn2W1[i * 8 + j], h1[j], s);
        h2L[wv][lane][i] = fmaxf(s, 0.f);
      }
    }
    __syncthreads();
    #pragma unroll
    for (int hf = 0; hf < 2; ++hf){
      int c = hf * 64 + lane;
      float4 w2a = *(const float4*)(wn2W2 + c * 8);
      float4 w2b = *(const float4*)(wn2W2 + c * 8 + 4);
      float accv = 0.f, bw = wn2b2[c];
      #pragma unroll
      for (int k = 0; k < 16; ++k){
        const float4 ha = *(const float4*)&h2L[wv][k][0];
        const float4 hb = *(const float4*)&h2L[wv][k][4];
        float w = bw;
        w = fmaf(w2a.x, ha.x, w); w = fmaf(w2a.y, ha.y, w); w = fmaf(w2a.z, ha.z, w); w = fmaf(w2a.w, ha.w, w);
        w = fmaf(w2b.x, hb.x, w); w = fmaf(w2b.y, hb.y, w); w = fmaf(w2b.z, hb.z, w); w = fmaf(w2b.w, hb.w, w);
        w = fmaxf(w, 0.f);
        float g = NF[(size_t)(base + idxL[wv][k]) * 128 + c];
        accv = fmaf(w, g, accv);
      }
      outT[c][np] = accv;
    }
    __syncthreads();
  }
  {
    int c = tid >> 1, jh = (tid & 1) * 8;
    float4 v0 = *(const float4*)&outT[c][jh];
    float4 v1 = *(const float4*)&outT[c][jh + 4];
    size_t ob = ((size_t)b * 128 + c) * NPTS + n0 + jh;
    *(float4*)(out + ob) = v0;
    *(float4*)(out + ob + 4) = v1;
  }
}

extern "C" void kernel_launch(void* const* d_in, const int* in_sizes, int n_in,
                              void* d_out, int out_size, void* d_ws, size_t ws_size,
                              hipStream_t stream)
{
  const float* pc1 = (const float*)d_in[0];
  const float* pc2 = (const float*)d_in[1];
  const float* f1  = (const float*)d_in[2];
  const float* f2  = (const float*)d_in[3];
  const float* mW0 = (const float*)d_in[4];
  const float* mb0 = (const float*)d_in[5];
  const float* mW1 = (const float*)d_in[6];
  const float* mb1 = (const float*)d_in[7];
  const float* w1W0 = (const float*)d_in[8];
  const float* w1b0 = (const float*)d_in[9];
  const float* w1W1 = (const float*)d_in[10];
  const float* w1b1 = (const float*)d_in[11];
  const float* w1W2 = (const float*)d_in[12];
  const float* w1b2 = (const float*)d_in[13];
  const float* w2W0 = (const float*)d_in[14];
  const float* w2b0 = (const float*)d_in[15];
  const float* w2W1 = (const float*)d_in[16];
  const float* w2b1 = (const float*)d_in[17];
  const float* w2W2 = (const float*)d_in[18];
  const float* w2b2 = (const float*)d_in[19];

  char* ws = (char*)d_ws;
  float4* p1f4 = (float4*)(ws + 0);
  float4* p2f4 = (float4*)(ws + 262144);
  ushort* f1b  = (ushort*)(ws + 524288);
  ushort* f2b  = (ushort*)(ws + 2621440);
  int* idx1    = (int*)(ws + 4718592);
  int* idx2    = (int*)(ws + 6815744);
  ushort* W0p  = (ushort*)(ws + 8912896);
  ushort* W1p  = (ushort*)(ws + 8953856);
  float* NF    = (float*)(ws + 8986624);
  float* out   = (float*)d_out;

  hipLaunchKernelGGL(k_misc, dim3(66), dim3(256), 0, stream, pc1, pc2, p1f4, p2f4, mW0, mW1, W0p, W1p);
  hipLaunchKernelGGL(k_transpose, dim3(128), dim3(256), 0, stream, f1, f2, f1b, f2b);
  hipLaunchKernelGGL(k_knn, dim3(2048), dim3(256), 0, stream, p1f4, p2f4, idx1, idx2);
  hipLaunchKernelGGL(k_fused, dim3(2048), dim3(256), 0, stream, p1f4, p2f4, f1b, f2b, idx1,
                     W0p, W1p, mb0, mb1, w1W0, w1b0, w1W1, w1b1, w1W2, w1b2, NF);
  hipLaunchKernelGGL(k_reagg, dim3(1024), dim3(256), 0, stream, p1f4, idx2, NF,
                     w2W0, w2b0, w2W1, w2b1, w2W2, w2b2, out);
}

// Round 6
// 348.702 us; speedup vs baseline: 2.0442x; 1.4144x over previous
//
#include <hip/hip_runtime.h>

typedef __attribute__((ext_vector_type(8))) short short8;
typedef __attribute__((ext_vector_type(4))) float f32x4;

#define NPTS 8192
#define NB 2
#define KNN 16
#define KP 20
#define LDX 168
#define LDH 136

__device__ inline ushort f2bf(float x){
  unsigned u = __float_as_uint(x);
  return (ushort)((u + 0x7FFFu + ((u >> 16) & 1u)) >> 16);
}
__device__ inline float leaky(float x){ return x > 0.f ? x : 0.1f * x; }
__device__ inline f32x4 mfma16(short8 a, short8 b, f32x4 c){
  return __builtin_amdgcn_mfma_f32_16x16x32_bf16(a, b, c, 0, 0, 0);
}
// 16^3 Morton cell key over [-3,3]^3 (must be identical in k_sort and k_knn)
__device__ inline int cellkey(float x, float y, float z){
  int ix = (int)((x + 3.f) * (16.f / 6.f));
  int iy = (int)((y + 3.f) * (16.f / 6.f));
  int iz = (int)((z + 3.f) * (16.f / 6.f));
  ix = ix < 0 ? 0 : (ix > 15 ? 15 : ix);
  iy = iy < 0 ? 0 : (iy > 15 ? 15 : iy);
  iz = iz < 0 ? 0 : (iz > 15 ? 15 : iz);
  int key = 0;
  #pragma unroll
  for (int i = 0; i < 4; ++i)
    key |= (((ix >> i) & 1) << (3 * i + 2)) | (((iy >> i) & 1) << (3 * i + 1)) | (((iz >> i) & 1) << (3 * i));
  return key;
}

// ---------------- misc: prep points (blocks 0..63) + pack W (blocks 64,65) ----------------
__global__ __launch_bounds__(256) void k_misc(const float* __restrict__ pc1, const float* __restrict__ pc2,
                                              float4* __restrict__ p1, float4* __restrict__ p2,
                                              const float* __restrict__ W0, const float* __restrict__ W1,
                                              ushort* __restrict__ W0p, ushort* __restrict__ W1p){
  int bid = blockIdx.x;
  if (bid < 64){
    int i = bid * 256 + threadIdx.x;
    int b = i >> 13, n = i & (NPTS - 1);
    const float* s1 = pc1 + (size_t)b * 3 * NPTS + n;
    const float* s2 = pc2 + (size_t)b * 3 * NPTS + n;
    p1[i] = make_float4(s1[0], s1[NPTS], s1[2 * NPTS], 0.f);
    p2[i] = make_float4(s2[0], s2[NPTS], s2[2 * NPTS], 0.f);
  } else if (bid == 64){
    for (int e = threadIdx.x; e < 8 * 5 * 64 * 8; e += 256){
      int i = e & 7, ln = (e >> 3) & 63, t = e >> 9, kt = t % 5, ct = t / 5;
      int col = ct * 16 + (ln & 15), k = kt * 32 + 8 * (ln >> 4) + i;
      W0p[e] = f2bf(k < 131 ? W0[col * 131 + k] : 0.f);
    }
  } else {
    for (int e = threadIdx.x; e < 8 * 4 * 64 * 8; e += 256){
      int i = e & 7, ln = (e >> 3) & 63, t = e >> 9, kt = t & 3, ct = t >> 2;
      int col = ct * 16 + (ln & 15), k = kt * 32 + 8 * (ln >> 4) + i;
      W1p[e] = f2bf(W1[col * 128 + k]);
    }
  }
}

// ---------------- transpose features [B,64,N] f32 -> [B,N,64] bf16 ----------------
__global__ __launch_bounds__(256) void k_transpose(const float* __restrict__ f1, const float* __restrict__ f2,
                                                   ushort* __restrict__ o1, ushort* __restrict__ o2){
  __shared__ ushort tile[64][257];
  int bid = blockIdx.x;
  int feat = bid >> 6; int b = (bid >> 5) & 1; int n0 = (bid & 31) * 256;
  const float* src = (feat ? f2 : f1) + (size_t)b * 64 * NPTS;
  ushort* dst = (feat ? o2 : o1) + (size_t)b * NPTS * 64;
  for (int rep = 0; rep < 64; ++rep){
    int lin = rep * 256 + threadIdx.x;
    int j = lin >> 8, nn = lin & 255;
    tile[j][nn] = f2bf(src[(size_t)j * NPTS + n0 + nn]);
  }
  __syncthreads();
  for (int rep = 0; rep < 64; ++rep){
    int lin = rep * 256 + threadIdx.x;
    int nn = lin >> 6, j = lin & 63;
    dst[(size_t)(n0 + nn) * 64 + j] = tile[j][nn];
  }
}

// ---------------- counting-sort points by Morton cell (one block per batch x cloud) ----------------
// Sort is perf-only: KNN scans all candidates regardless, so exactness never depends on it.
__global__ __launch_bounds__(1024) void k_sort(const float4* __restrict__ p1, const float4* __restrict__ p2,
                                               float4* __restrict__ sp1, float4* __restrict__ sp2,
                                               int* __restrict__ cs1, int* __restrict__ cs2){
  __shared__ int hist[4096];
  __shared__ int tsum[1024];
  int bid = blockIdx.x;            // 0..3
  int b = bid >> 1, cloud = bid & 1;
  const float4* src = (cloud ? p2 : p1) + b * NPTS;
  float4* dst = (cloud ? sp2 : sp1) + b * NPTS;
  int* cs = (cloud ? cs2 : cs1) + b * 4100;
  int tid = threadIdx.x;
  #pragma unroll
  for (int i = 0; i < 4; ++i) hist[tid + i * 1024] = 0;
  __syncthreads();
  int keys[8];
  #pragma unroll
  for (int i = 0; i < 8; ++i){
    float4 v = src[i * 1024 + tid];
    keys[i] = cellkey(v.x, v.y, v.z);
    atomicAdd(&hist[keys[i]], 1);
  }
  __syncthreads();
  int h[4], s = 0;
  #pragma unroll
  for (int i = 0; i < 4; ++i){ h[i] = hist[tid * 4 + i]; s += h[i]; }
  tsum[tid] = s;
  __syncthreads();
  for (int off = 1; off < 1024; off <<= 1){
    int v = tsum[tid];
    if (tid >= off) v += tsum[tid - off];
    __syncthreads();
    tsum[tid] = v;
    __syncthreads();
  }
  int ex = tid ? tsum[tid - 1] : 0;
  #pragma unroll
  for (int i = 0; i < 4; ++i){ int c = h[i]; hist[tid * 4 + i] = ex; cs[tid * 4 + i] = ex; ex += c; }
  if (tid == 1023) cs[4096] = NPTS;
  __syncthreads();
  #pragma unroll
  for (int i = 0; i < 8; ++i){
    float4 v = src[i * 1024 + tid];
    int pos = atomicAdd(&hist[keys[i]], 1);
    dst[pos] = make_float4(v.x, v.y, v.z, __int_as_float(i * 1024 + tid));
  }
}

// ---------------- exact KNN with seeded threshold ----------------
// task 0: q=p1, c=sorted p2 -> idx1 ; task 1: q=p1, c=sorted p1 -> idx2
// Seed: 256-pt Morton window -> per-lane min4 -> bitonic sort 64 -> thr0 (>= true v20, +1ulp)
// Main scan: exhaustive, threshold-gated inserts (exact); fp64 rerank of top-20 -> top-16.
__global__ __launch_bounds__(256) void k_knn(const float4* __restrict__ p1,
                                             const float4* __restrict__ sp1, const float4* __restrict__ sp2,
                                             const int* __restrict__ cs1, const int* __restrict__ cs2,
                                             int* __restrict__ idx1, int* __restrict__ idx2){
  __shared__ float sx[1024], sy[1024], sz[1024];
  int tid = threadIdx.x, lane = tid & 63, wv = tid >> 6;
  int bid = blockIdx.x;
  int task = bid >> 10, rem = bid & 1023;
  int b = rem >> 9; int q0 = (rem & 511) * 16;
  const float4* __restrict__ cpb = (task ? sp1 : sp2) + b * NPTS;
  const int* __restrict__ cs = (task ? cs1 : cs2) + b * 4100;
  int* __restrict__ outIdx = task ? idx2 : idx1;
  int qbase = b * NPTS + q0 + wv * 4;
  float qx[4], qy[4], qz[4], sd[4], thr[4]; int si[4];
  #pragma unroll
  for (int i = 0; i < 4; ++i){
    float4 qq = p1[qbase + i];
    qx[i] = qq.x; qy[i] = qq.y; qz[i] = qq.z;
  }
  // ---- seed thr0 per query ----
  #pragma unroll
  for (int q = 0; q < 4; ++q){
    int key = cellkey(qx[q], qy[q], qz[q]);
    int st = cs[key], en = cs[key + 1];
    int wstart = st + ((en - st) >> 1) - 128;
    wstart = wstart < 0 ? 0 : (wstart > NPTS - 256 ? NPTS - 256 : wstart);
    float mn = 1e30f;
    #pragma unroll
    for (int i = 0; i < 4; ++i){
      float4 c = cpb[wstart + i * 64 + lane];
      float dx = c.x - qx[q], dy = c.y - qy[q], dz = c.z - qz[q];
      mn = fminf(mn, fmaf(dx, dx, fmaf(dy, dy, dz * dz)));
    }
    float v = mn;
    #pragma unroll
    for (int k = 2; k <= 64; k <<= 1){
      #pragma unroll
      for (int j = k >> 1; j > 0; j >>= 1){
        float o = __shfl_xor(v, j);
        bool asc = ((lane & k) == 0);
        bool upper = ((lane & j) != 0);
        v = (asc != upper) ? fminf(v, o) : fmaxf(v, o);
      }
    }
    float t0 = __shfl(v, KP - 1);
    thr[q] = __uint_as_float(__float_as_uint(t0) + 1u);  // +1 ulp: >=20 candidates strictly below
    sd[q] = 1e30f; si[q] = 0;
  }
  // ---- exhaustive scan ----
  for (int ch = 0; ch < 8; ++ch){
    __syncthreads();
    for (int t = tid; t < 1024; t += 256){
      float4 cc = cpb[ch * 1024 + t];
      sx[t] = cc.x; sy[t] = cc.y; sz[t] = cc.z;
    }
    __syncthreads();
    for (int it = 0; it < 16; ++it){
      float cx = sx[it * 64 + lane], cy = sy[it * 64 + lane], cz = sz[it * 64 + lane];
      int jb = ch * 1024 + it * 64;
      #pragma unroll
      for (int q = 0; q < 4; ++q){
        float dx = cx - qx[q], dy = cy - qy[q], dz = cz - qz[q];
        float d = fmaf(dx, dx, fmaf(dy, dy, dz * dz));
        unsigned long long m = __ballot(d < thr[q]);
        while (m){
          int src = __ffsll((unsigned long long)m) - 1;
          m &= m - 1;
          float dv = __shfl(d, src);
          if (dv >= thr[q]) continue;
          int iv = jb + src;
          float ud = __shfl_up(sd[q], 1);
          int   ui = __shfl_up(si[q], 1);
          int pos = __popcll(__ballot(sd[q] <= dv) & 0xFFFFFull);
          bool lt = lane < pos;
          bool eq = lane == pos;
          float nd = lt ? sd[q] : (eq ? dv : ud);
          int   ni = lt ? si[q] : (eq ? iv : ui);
          sd[q] = nd; si[q] = ni;
          thr[q] = fminf(thr[q], __shfl(nd, KP - 1));
        }
      }
    }
  }
  // ---- fp64 rerank: keep 16 smallest of the 20; output ORIGINAL indices ----
  #pragma unroll
  for (int q = 0; q < 4; ++q){
    double dd = -1.0;
    int myi = si[q];
    int orig = 0;
    if (lane < KP){
      float4 cc = cpb[myi];
      orig = __float_as_int(cc.w);
      double dx = (double)cc.x - (double)qx[q];
      double dy = (double)cc.y - (double)qy[q];
      double dz = (double)cc.z - (double)qz[q];
      dd = dx * dx + dy * dy + dz * dz;
    }
    #pragma unroll
    for (int rep = 0; rep < 4; ++rep){
      double mx = dd; int mi = lane;
      #pragma unroll
      for (int off = 32; off; off >>= 1){
        double om = __shfl_xor(mx, off);
        int oi = __shfl_xor(mi, off);
        if (om > mx || (om == mx && oi < mi)){ mx = om; mi = oi; }
      }
      if (lane == mi) dd = -1.0;
    }
    unsigned long long keep = __ballot(dd >= 0.0);
    int rank = __popcll(keep & ((1ull << lane) - 1ull));
    if (dd >= 0.0) outIdx[(size_t)(b * NPTS + q0 + wv * 4 + q) * KNN + rank] = orig;
  }
}

// ---------------- fused: gather X, MLP(131->128->128) via MFMA, wn1, k-reduce -> NF ----------------
__global__ __launch_bounds__(256) void k_fused(
    const float4* __restrict__ p1, const float4* __restrict__ p2,
    const ushort* __restrict__ f1b, const ushort* __restrict__ f2b,
    const int* __restrict__ idx1,
    const ushort* __restrict__ W0p, const ushort* __restrict__ W1p,
    const float* __restrict__ b0, const float* __restrict__ b1,
    const float* __restrict__ wn1W0, const float* __restrict__ wn1b0,
    const float* __restrict__ wn1W1, const float* __restrict__ wn1b1,
    const float* __restrict__ wn1W2, const float* __restrict__ wn1b2,
    float* __restrict__ NF)
{
  __shared__ ushort Xs[128 * LDX];     // overlaid by H after GEMM1
  __shared__ float dirS[128][4];
  __shared__ float h2S[128][8];
  __shared__ float W2s[128][8];
  __shared__ float b0S[128], b1S[128], b2S[128];
  __shared__ int idxS[128];
  int tid = threadIdx.x, lane = tid & 63, wv = tid >> 6;
  int bid = blockIdx.x;
  int b = bid >> 10; int n0 = (bid & 1023) << 3;
  int base = b * NPTS;
  for (int t = tid; t < 1024; t += 256) ((float*)W2s)[t] = wn1W2[t];
  if (tid < 128){
    b0S[tid] = b0[tid]; b1S[tid] = b1[tid]; b2S[tid] = wn1b2[tid];
    int p = tid >> 4;
    int id = idx1[(size_t)(base + n0 + p) * KNN + (tid & 15)];
    idxS[tid] = id;
    float4 c = p2[base + id];
    float4 q = p1[base + n0 + p];
    float dx = c.x - q.x, dy = c.y - q.y, dz = c.z - q.z;
    dirS[tid][0] = dx; dirS[tid][1] = dy; dirS[tid][2] = dz; dirS[tid][3] = 0.f;
    ushort* xr = Xs + tid * LDX;
    xr[128] = f2bf(dx); xr[129] = f2bf(dy); xr[130] = f2bf(dz);
    #pragma unroll
    for (int j = 131; j < 160; ++j) xr[j] = 0;
  }
  __syncthreads();
  {
    // each half-row is 64 bf16 = 128 bytes = 8 x uint4
    int r = tid >> 1, hf = tid & 1;
    const uint4* s = (const uint4*)(hf ? (f2b + (size_t)(base + idxS[r]) * 64)
                                       : (f1b + (size_t)(base + n0 + (r >> 4)) * 64));
    uint4* d = (uint4*)(Xs + r * LDX + hf * 64);
    #pragma unroll
    for (int j = 0; j < 8; ++j) d[j] = s[j];
  }
  __syncthreads();
  int r0 = wv * 32;
  f32x4 zero4 = {0.f, 0.f, 0.f, 0.f};
  f32x4 acc[2][8];
  #pragma unroll
  for (int mt = 0; mt < 2; ++mt)
    #pragma unroll
    for (int ct = 0; ct < 8; ++ct) acc[mt][ct] = zero4;
  #pragma unroll
  for (int kt = 0; kt < 5; ++kt){
    const ushort* ab = Xs + (r0 + (lane & 15)) * LDX + kt * 32 + 8 * (lane >> 4);
    short8 a0 = *(const short8*)ab;
    short8 a1 = *(const short8*)(ab + 16 * LDX);
    #pragma unroll
    for (int ct = 0; ct < 8; ++ct){
      short8 bb = *(const short8*)(W0p + (size_t)((ct * 5 + kt) * 64 + lane) * 8);
      acc[0][ct] = mfma16(a0, bb, acc[0][ct]);
      acc[1][ct] = mfma16(a1, bb, acc[1][ct]);
    }
  }
  __syncthreads();   // all X reads done; reuse as H
  ushort* Hs = Xs;
  #pragma unroll
  for (int mt = 0; mt < 2; ++mt)
    #pragma unroll
    for (int ct = 0; ct < 8; ++ct){
      int col = ct * 16 + (lane & 15);
      float bb = b0S[col];
      #pragma unroll
      for (int r = 0; r < 4; ++r){
        int row = r0 + mt * 16 + 4 * (lane >> 4) + r;
        Hs[row * LDH + col] = f2bf(leaky(acc[mt][ct][r] + bb));
      }
    }
  // wn1 hidden layers (fp32, per-row)
  if (tid < 128){
    float d0 = dirS[tid][0], d1 = dirS[tid][1], d2 = dirS[tid][2];
    float h1[8];
    #pragma unroll
    for (int i = 0; i < 8; ++i)
      h1[i] = fmaxf(fmaf(wn1W0[i * 3 + 2], d2, fmaf(wn1W0[i * 3 + 1], d1, fmaf(wn1W0[i * 3], d0, wn1b0[i]))), 0.f);
    #pragma unroll
    for (int i = 0; i < 8; ++i){
      float s = wn1b1[i];
      #pragma unroll
      for (int j = 0; j < 8; ++j) s = fmaf(wn1W1[i * 8 + j], h1[j], s);
      h2S[tid][i] = fmaxf(s, 0.f);
    }
  }
  __syncthreads();
  // GEMM2
  #pragma unroll
  for (int mt = 0; mt < 2; ++mt)
    #pragma unroll
    for (int ct = 0; ct < 8; ++ct) acc[mt][ct] = zero4;
  #pragma unroll
  for (int kt = 0; kt < 4; ++kt){
    const ushort* ab = Hs + (r0 + (lane & 15)) * LDH + kt * 32 + 8 * (lane >> 4);
    short8 a0 = *(const short8*)ab;
    short8 a1 = *(const short8*)(ab + 16 * LDH);
    #pragma unroll
    for (int ct = 0; ct < 8; ++ct){
      short8 bb = *(const short8*)(W1p + (size_t)((ct * 4 + kt) * 64 + lane) * 8);
      acc[0][ct] = mfma16(a0, bb, acc[0][ct]);
      acc[1][ct] = mfma16(a1, bb, acc[1][ct]);
    }
  }
  // epilogue: w = relu(wn1 layer3), g = leaky(acc+b1), reduce over k
  #pragma unroll
  for (int ct = 0; ct < 8; ++ct){
    int col = ct * 16 + (lane & 15);
    float4 w2a = *(const float4*)&W2s[col][0];
    float4 w2b = *(const float4*)&W2s[col][4];
    float bw = b2S[col], bg = b1S[col];
    #pragma unroll
    for (int mt = 0; mt < 2; ++mt){
      float s = 0.f;
      #pragma unroll
      for (int r = 0; r < 4; ++r){
        int row = r0 + mt * 16 + 4 * (lane >> 4) + r;
        const float4 ha = *(const float4*)&h2S[row][0];
        const float4 hb = *(const float4*)&h2S[row][4];
        float w = bw;
        w = fmaf(w2a.x, ha.x, w); w = fmaf(w2a.y, ha.y, w); w = fmaf(w2a.z, ha.z, w); w = fmaf(w2a.w, ha.w, w);
        w = fmaf(w2b.x, hb.x, w); w = fmaf(w2b.y, hb.y, w); w = fmaf(w2b.z, hb.z, w); w = fmaf(w2b.w, hb.w, w);
        w = fmaxf(w, 0.f);
        float g = leaky(acc[mt][ct][r] + bg);
        s = fmaf(w, g, s);
      }
      s += __shfl_xor(s, 16);
      s += __shfl_xor(s, 32);
      if (lane < 16) NF[(size_t)(base + n0 + wv * 2 + mt) * 128 + col] = s;
    }
  }
}

// ---------------- re-aggregation: wn2 weights + NF gather, transposed store ----------------
__global__ __launch_bounds__(256) void k_reagg(
    const float4* __restrict__ p1, const int* __restrict__ idx2,
    const float* __restrict__ NF,
    const float* __restrict__ wn2W0, const float* __restrict__ wn2b0,
    const float* __restrict__ wn2W1, const float* __restrict__ wn2b1,
    const float* __restrict__ wn2W2, const float* __restrict__ wn2b2,
    float* __restrict__ out)
{
  __shared__ float h2L[4][16][8];
  __shared__ int idxL[4][16];
  __shared__ float outT[128][20];
  int tid = threadIdx.x, lane = tid & 63, wv = tid >> 6;
  int bid = blockIdx.x;
  int b = bid >> 9; int n0 = (bid & 511) * 16;
  int base = b * NPTS;
  for (int pp = 0; pp < 4; ++pp){
    int np = wv * 4 + pp;
    int n = n0 + np;
    if (lane < 16){
      int id = idx2[(size_t)(base + n) * KNN + lane];
      idxL[wv][lane] = id;
      float4 c = p1[base + id];
      float4 q = p1[base + n];
      float d0 = c.x - q.x, d1 = c.y - q.y, d2 = c.z - q.z;
      float h1[8];
      #pragma unroll
      for (int i = 0; i < 8; ++i)
        h1[i] = fmaxf(fmaf(wn2W0[i * 3 + 2], d2, fmaf(wn2W0[i * 3 + 1], d1, fmaf(wn2W0[i * 3], d0, wn2b0[i]))), 0.f);
      #pragma unroll
      for (int i = 0; i < 8; ++i){
        float s = wn2b1[i];
        #pragma unroll
        for (int j = 0; j < 8; ++j) s = fmaf(wn2W1[i * 8 + j], h1[j], s);
        h2L[wv][lane][i] = fmaxf(s, 0.f);
      }
    }
    __syncthreads();
    #pragma unroll
    for (int hf = 0; hf < 2; ++hf){
      int c = hf * 64 + lane;
      float4 w2a = *(const float4*)(wn2W2 + c * 8);
      float4 w2b = *(const float4*)(wn2W2 + c * 8 + 4);
      float accv = 0.f, bw = wn2b2[c];
      #pragma unroll
      for (int k = 0; k < 16; ++k){
        const float4 ha = *(const float4*)&h2L[wv][k][0];
        const float4 hb = *(const float4*)&h2L[wv][k][4];
        float w = bw;
        w = fmaf(w2a.x, ha.x, w); w = fmaf(w2a.y, ha.y, w); w = fmaf(w2a.z, ha.z, w); w = fmaf(w2a.w, ha.w, w);
        w = fmaf(w2b.x, hb.x, w); w = fmaf(w2b.y, hb.y, w); w = fmaf(w2b.z, hb.z, w); w = fmaf(w2b.w, hb.w, w);
        w = fmaxf(w, 0.f);
        float g = NF[(size_t)(base + idxL[wv][k]) * 128 + c];
        accv = fmaf(w, g, accv);
      }
      outT[c][np] = accv;
    }
    __syncthreads();
  }
  {
    int c = tid >> 1, jh = (tid & 1) * 8;
    float4 v0 = *(const float4*)&outT[c][jh];
    float4 v1 = *(const float4*)&outT[c][jh + 4];
    size_t ob = ((size_t)b * 128 + c) * NPTS + n0 + jh;
    *(float4*)(out + ob) = v0;
    *(float4*)(out + ob + 4) = v1;
  }
}

extern "C" void kernel_launch(void* const* d_in, const int* in_sizes, int n_in,
                              void* d_out, int out_size, void* d_ws, size_t ws_size,
                              hipStream_t stream)
{
  const float* pc1 = (const float*)d_in[0];
  const float* pc2 = (const float*)d_in[1];
  const float* f1  = (const float*)d_in[2];
  const float* f2  = (const float*)d_in[3];
  const float* mW0 = (const float*)d_in[4];
  const float* mb0 = (const float*)d_in[5];
  const float* mW1 = (const float*)d_in[6];
  const float* mb1 = (const float*)d_in[7];
  const float* w1W0 = (const float*)d_in[8];
  const float* w1b0 = (const float*)d_in[9];
  const float* w1W1 = (const float*)d_in[10];
  const float* w1b1 = (const float*)d_in[11];
  const float* w1W2 = (const float*)d_in[12];
  const float* w1b2 = (const float*)d_in[13];
  const float* w2W0 = (const float*)d_in[14];
  const float* w2b0 = (const float*)d_in[15];
  const float* w2W1 = (const float*)d_in[16];
  const float* w2b1 = (const float*)d_in[17];
  const float* w2W2 = (const float*)d_in[18];
  const float* w2b2 = (const float*)d_in[19];

  char* ws = (char*)d_ws;
  float4* p1f4 = (float4*)(ws + 0);
  float4* p2f4 = (float4*)(ws + 262144);
  ushort* f1b  = (ushort*)(ws + 524288);
  ushort* f2b  = (ushort*)(ws + 2621440);
  int* idx1    = (int*)(ws + 4718592);
  int* idx2    = (int*)(ws + 6815744);
  ushort* W0p  = (ushort*)(ws + 8912896);
  ushort* W1p  = (ushort*)(ws + 8953856);
  float* NF    = (float*)(ws + 8986624);
  // sorted arrays + cell starts overlay NF's region (dead until k_fused, which runs after k_knn)
  float4* sp1  = (float4*)(ws + 8986624);
  float4* sp2  = (float4*)(ws + 9248768);
  int* cs1     = (int*)(ws + 9510912);
  int* cs2     = (int*)(ws + 9543712);
  float* out   = (float*)d_out;

  hipLaunchKernelGGL(k_misc, dim3(66), dim3(256), 0, stream, pc1, pc2, p1f4, p2f4, mW0, mW1, W0p, W1p);
  hipLaunchKernelGGL(k_sort, dim3(4), dim3(1024), 0, stream, p1f4, p2f4, sp1, sp2, cs1, cs2);
  hipLaunchKernelGGL(k_transpose, dim3(128), dim3(256), 0, stream, f1, f2, f1b, f2b);
  hipLaunchKernelGGL(k_knn, dim3(2048), dim3(256), 0, stream, p1f4, sp1, sp2, cs1, cs2, idx1, idx2);
  hipLaunchKernelGGL(k_fused, dim3(2048), dim3(256), 0, stream, p1f4, p2f4, f1b, f2b, idx1,
                     W0p, W1p, mb0, mb1, w1W0, w1b0, w1W1, w1b1, w1W2, w1b2, NF);
  hipLaunchKernelGGL(k_reagg, dim3(1024), dim3(256), 0, stream, p1f4, idx2, NF,
                     w2W0, w2b0, w2W1, w2b1, w2W2, w2b2, out);
}